// Round 1
// baseline (2231.716 us; speedup 1.0000x reference)
//
#include <hip/hip_runtime.h>
#include <hip/hip_bf16.h>
#include <math.h>

// ---------------------------------------------------------------------------
// MoGCN: two 2-layer GCN branches (H=64) + concat + FC(128->4), fp32.
// Round 0: correctness-first structured implementation.
//   - deg/dinv via atomics, self-loop folded into dinv
//   - tiled fp32 GEMM (no fp32 MFMA on CDNA4 -> vector ALU)
//   - edge aggregation: 1 wave per edge, lane=feature, atomicAdd scatter
// ---------------------------------------------------------------------------

#define H 64

static inline int ceil_div(int a, int b) { return (a + b - 1) / b; }

// ---- degree ---------------------------------------------------------------
__global__ __launch_bounds__(256) void deg_kernel(const int* __restrict__ dst,
                                                  float* __restrict__ deg, int E) {
    int e = blockIdx.x * 256 + threadIdx.x;
    if (e < E) atomicAdd(&deg[dst[e]], 1.0f);
}

__global__ __launch_bounds__(256) void dinv_kernel(float* __restrict__ deg, int n) {
    int i = blockIdx.x * 256 + threadIdx.x;
    if (i < n) deg[i] = rsqrtf(deg[i] + 1.0f);  // +1 = self loop; deg>=1 always
}

// ---- GEMM: Hout[M,64] = X[M,K] @ W[K,64] ----------------------------------
// BM=64, BN=64, BK=32; 256 threads; 4x4 register micro-tile per thread.
#define BM 64
#define BN 64
#define BK 32
__global__ __launch_bounds__(256) void gemm64_kernel(const float* __restrict__ X,
                                                     const float* __restrict__ W,
                                                     float* __restrict__ Hout,
                                                     int M, int K) {
    __shared__ float Xs[BK][BM + 1];  // [kk][row], +1 pad breaks bank conflicts
    __shared__ float Ws[BK][BN];      // [kk][col]

    const int tid = threadIdx.x;
    const int block_row = blockIdx.x * BM;
    const int tx = tid & 15;   // col group: 16 groups of 4 cols
    const int ty = tid >> 4;   // row group: 16 groups of 4 rows

    float acc[4][4] = {{0.f}};

    for (int kb = 0; kb < K; kb += BK) {
        // load X tile (BM x BK = 2048 floats, 8 per thread, coalesced in k)
#pragma unroll
        for (int i = 0; i < 8; ++i) {
            int idx = tid + i * 256;
            int r   = idx >> 5;        // / BK
            int kk  = idx & (BK - 1);
            int gr  = block_row + r;
            float v = 0.f;
            if (gr < M) v = X[(size_t)gr * K + kb + kk];
            Xs[kk][r] = v;
        }
        // load W tile (BK x BN = 2048 floats, coalesced in col)
#pragma unroll
        for (int i = 0; i < 8; ++i) {
            int idx = tid + i * 256;
            int kk  = idx >> 6;        // / BN
            int c   = idx & (BN - 1);
            Ws[kk][c] = W[(size_t)(kb + kk) * BN + c];
        }
        __syncthreads();

#pragma unroll
        for (int kk = 0; kk < BK; ++kk) {
            float xr[4], wc[4];
#pragma unroll
            for (int i = 0; i < 4; ++i) xr[i] = Xs[kk][ty * 4 + i];
#pragma unroll
            for (int j = 0; j < 4; ++j) wc[j] = Ws[kk][tx * 4 + j];
#pragma unroll
            for (int i = 0; i < 4; ++i)
#pragma unroll
                for (int j = 0; j < 4; ++j)
                    acc[i][j] += xr[i] * wc[j];
        }
        __syncthreads();
    }

#pragma unroll
    for (int i = 0; i < 4; ++i) {
        int gr = block_row + ty * 4 + i;
        if (gr < M) {
#pragma unroll
            for (int j = 0; j < 4; ++j)
                Hout[(size_t)gr * H + tx * 4 + j] = acc[i][j];
        }
    }
}

// ---- aggregation ----------------------------------------------------------
// init agg with the self-loop contribution (also serves as zero-init of ws)
__global__ __launch_bounds__(256) void selfloop_init_kernel(const float* __restrict__ h,
                                                            const float* __restrict__ dinv,
                                                            float* __restrict__ agg,
                                                            int n64) {
    int i = blockIdx.x * 256 + threadIdx.x;
    if (i >= n64) return;
    int node = i >> 6;
    float dv = dinv[node];
    agg[i] = h[i] * dv * dv;
}

// one wave (64 lanes) per edge; lane = feature index
__global__ __launch_bounds__(256) void edge_agg_kernel(const int* __restrict__ src,
                                                       const int* __restrict__ dst,
                                                       const float* __restrict__ dinv,
                                                       const float* __restrict__ h,
                                                       float* __restrict__ agg, int E) {
    int lane = threadIdx.x & 63;
    int e = blockIdx.x * 4 + (threadIdx.x >> 6);
    if (e >= E) return;
    int s = src[e];
    int d = dst[e];
    float nrm = dinv[s] * dinv[d];
    float v = h[(size_t)s * H + lane] * nrm;
    atomicAdd(&agg[(size_t)d * H + lane], v);
}

// ---- bias + ELU (in place) ------------------------------------------------
__global__ __launch_bounds__(256) void bias_elu_kernel(float* __restrict__ x,
                                                       const float* __restrict__ b,
                                                       int n64) {
    int i = blockIdx.x * 256 + threadIdx.x;
    if (i >= n64) return;
    float v = x[i] + b[i & 63];
    x[i] = v > 0.f ? v : (expf(v) - 1.0f);
}

// ---- final FC: out[n,c] = [x1|x2][n,:] @ Wfc + bfc ------------------------
// one wave per node; lane k holds partial products; shfl reduce
__global__ __launch_bounds__(256) void fc_kernel(const float* __restrict__ x1,
                                                 const float* __restrict__ x2,
                                                 const float* __restrict__ Wfc,
                                                 const float* __restrict__ bfc,
                                                 float* __restrict__ out, int n) {
    int lane = threadIdx.x & 63;
    int node = blockIdx.x * 4 + (threadIdx.x >> 6);
    if (node >= n) return;
    float v1 = x1[(size_t)node * H + lane];
    float v2 = x2[(size_t)node * H + lane];
    float a[4];
#pragma unroll
    for (int c = 0; c < 4; ++c)
        a[c] = v1 * Wfc[lane * 4 + c] + v2 * Wfc[(H + lane) * 4 + c];
#pragma unroll
    for (int off = 32; off > 0; off >>= 1) {
#pragma unroll
        for (int c = 0; c < 4; ++c)
            a[c] += __shfl_down(a[c], off, 64);
    }
    if (lane == 0) {
#pragma unroll
        for (int c = 0; c < 4; ++c)
            out[(size_t)node * 4 + c] = a[c] + bfc[c];
    }
}

// ---------------------------------------------------------------------------
extern "C" void kernel_launch(void* const* d_in, const int* in_sizes, int n_in,
                              void* d_out, int out_size, void* d_ws, size_t ws_size,
                              hipStream_t stream) {
    const float* x_omic1 = (const float*)d_in[0];
    const float* x_omic2 = (const float*)d_in[1];
    const int*   eidx    = (const int*)d_in[2];
    const float* W1a = (const float*)d_in[3];
    const float* b1a = (const float*)d_in[4];
    const float* W2a = (const float*)d_in[5];
    const float* b2a = (const float*)d_in[6];
    const float* W1b = (const float*)d_in[7];
    const float* b1b = (const float*)d_in[8];
    const float* W2b = (const float*)d_in[9];
    const float* b2b = (const float*)d_in[10];
    const float* Wfc = (const float*)d_in[11];
    const float* bfc = (const float*)d_in[12];
    float* out = (float*)d_out;

    const int D1 = 512, D2 = 256;
    const int N = in_sizes[0] / D1;
    const int E = in_sizes[2] / 2;
    const int* src = eidx;
    const int* dst = eidx + E;

    // workspace layout (fp32): dinv[N] | bufA[N*64] | bufB[N*64] | bufC[N*64]
    float* dinv = (float*)d_ws;
    float* bufA = dinv + N;             // N*4 bytes offset, 16B aligned (N=100000)
    float* bufB = bufA + (size_t)N * H;
    float* bufC = bufB + (size_t)N * H;

    const int n64 = N * H;
    dim3 blk(256);
    dim3 grid_e(ceil_div(E, 256));
    dim3 grid_n(ceil_div(N, 256));
    dim3 grid_n64(ceil_div(n64, 256));
    dim3 grid_edge(ceil_div(E, 4));     // 4 edges (waves) per block
    dim3 grid_node(ceil_div(N, 4));
    dim3 grid_gemm(ceil_div(N, BM));

    // degree / dinv  (ws is poisoned each call -> must memset)
    hipMemsetAsync(dinv, 0, (size_t)N * sizeof(float), stream);
    deg_kernel<<<grid_e, blk, 0, stream>>>(dst, dinv, E);
    dinv_kernel<<<grid_n, blk, 0, stream>>>(dinv, N);

    // ---- branch 1: omic1 ----
    gemm64_kernel<<<grid_gemm, blk, 0, stream>>>(x_omic1, W1a, bufA, N, D1);
    selfloop_init_kernel<<<grid_n64, blk, 0, stream>>>(bufA, dinv, bufB, n64);
    edge_agg_kernel<<<grid_edge, blk, 0, stream>>>(src, dst, dinv, bufA, bufB, E);
    bias_elu_kernel<<<grid_n64, blk, 0, stream>>>(bufB, b1a, n64);

    gemm64_kernel<<<grid_gemm, blk, 0, stream>>>(bufB, W2a, bufA, N, H);
    selfloop_init_kernel<<<grid_n64, blk, 0, stream>>>(bufA, dinv, bufC, n64);
    edge_agg_kernel<<<grid_edge, blk, 0, stream>>>(src, dst, dinv, bufA, bufC, E);
    bias_elu_kernel<<<grid_n64, blk, 0, stream>>>(bufC, b2a, n64);   // x1 -> bufC

    // ---- branch 2: omic2 ----
    gemm64_kernel<<<grid_gemm, blk, 0, stream>>>(x_omic2, W1b, bufA, N, D2);
    selfloop_init_kernel<<<grid_n64, blk, 0, stream>>>(bufA, dinv, bufB, n64);
    edge_agg_kernel<<<grid_edge, blk, 0, stream>>>(src, dst, dinv, bufA, bufB, E);
    bias_elu_kernel<<<grid_n64, blk, 0, stream>>>(bufB, b1b, n64);

    gemm64_kernel<<<grid_gemm, blk, 0, stream>>>(bufB, W2b, bufA, N, H);
    selfloop_init_kernel<<<grid_n64, blk, 0, stream>>>(bufA, dinv, bufB, n64);
    edge_agg_kernel<<<grid_edge, blk, 0, stream>>>(src, dst, dinv, bufA, bufB, E);
    bias_elu_kernel<<<grid_n64, blk, 0, stream>>>(bufB, b2b, n64);   // x2 -> bufB

    // ---- FC head ----
    fc_kernel<<<grid_node, blk, 0, stream>>>(bufC, bufB, Wfc, bfc, out, N);
}

// Round 2
// 1358.626 us; speedup vs baseline: 1.6426x; 1.6426x over previous
//
#include <hip/hip_runtime.h>
#include <hip/hip_bf16.h>
#include <math.h>

// ---------------------------------------------------------------------------
// MoGCN: two 2-layer GCN branches (H=64) + concat + FC(128->4), fp32.
// Round 1: replace atomic scatter-aggregation (400 MB HBM write-through per
// layer, 4x336us) with per-call CSR build (counting sort by dst) + gather
// aggregation fused with self-loop + bias + ELU.
// ---------------------------------------------------------------------------

#define H 64

static inline int ceil_div(int a, int b) { return (a + b - 1) / b; }

// ---- degree (int histogram over dst) --------------------------------------
__global__ __launch_bounds__(256) void deg_kernel(const int* __restrict__ dst,
                                                  int* __restrict__ deg, int E) {
    int e = blockIdx.x * 256 + threadIdx.x;
    if (e < E) atomicAdd(&deg[dst[e]], 1);
}

__global__ __launch_bounds__(256) void dinv_kernel(const int* __restrict__ deg,
                                                   float* __restrict__ dinv, int n) {
    int i = blockIdx.x * 256 + threadIdx.x;
    if (i < n) dinv[i] = rsqrtf((float)deg[i] + 1.0f);  // +1 = self loop
}

// ---- exclusive scan of deg -> row_ptr (3-kernel hierarchical) -------------
__global__ __launch_bounds__(256) void scan_block_kernel(const int* __restrict__ deg,
                                                         int* __restrict__ row_partial,
                                                         int* __restrict__ blocksums,
                                                         int n) {
    __shared__ int s[256];
    int i = blockIdx.x * 256 + threadIdx.x;
    int v = (i < n) ? deg[i] : 0;
    s[threadIdx.x] = v;
    __syncthreads();
#pragma unroll
    for (int off = 1; off < 256; off <<= 1) {
        int t = (threadIdx.x >= off) ? s[threadIdx.x - off] : 0;
        __syncthreads();
        s[threadIdx.x] += t;
        __syncthreads();
    }
    if (i < n) row_partial[i] = s[threadIdx.x] - v;  // exclusive
    if (threadIdx.x == 255) blocksums[blockIdx.x] = s[255];
}

__global__ __launch_bounds__(512) void scan_top_kernel(int* __restrict__ blocksums,
                                                       int nb) {
    __shared__ int s[512];
    int v = (threadIdx.x < (unsigned)nb) ? blocksums[threadIdx.x] : 0;
    s[threadIdx.x] = v;
    __syncthreads();
#pragma unroll
    for (int off = 1; off < 512; off <<= 1) {
        int t = (threadIdx.x >= off) ? s[threadIdx.x - off] : 0;
        __syncthreads();
        s[threadIdx.x] += t;
        __syncthreads();
    }
    if (threadIdx.x < (unsigned)nb) blocksums[threadIdx.x] = s[threadIdx.x] - v;
}

// finalize row_ptr, init cursor (=row_ptr), set row_ptr[n]=E
__global__ __launch_bounds__(256) void scan_add_kernel(int* __restrict__ row_ptr,
                                                       const int* __restrict__ blocksums,
                                                       int* __restrict__ cursor,
                                                       int n, int E) {
    int i = blockIdx.x * 256 + threadIdx.x;
    if (i < n) {
        int v = row_ptr[i] + blocksums[blockIdx.x];
        row_ptr[i] = v;
        cursor[i] = v;
    }
    if (i == 0) row_ptr[n] = E;
}

// ---- scatter edges into CSR order -----------------------------------------
__global__ __launch_bounds__(256) void scatter_kernel(const int* __restrict__ src,
                                                      const int* __restrict__ dst,
                                                      int* __restrict__ cursor,
                                                      int* __restrict__ csr_src, int E) {
    int e = blockIdx.x * 256 + threadIdx.x;
    if (e >= E) return;
    int d = dst[e];
    int pos = atomicAdd(&cursor[d], 1);
    csr_src[pos] = src[e];
}

// ---- GEMM: Hout[M,64] = X[M,K] @ W[K,64] ----------------------------------
#define BM 64
#define BN 64
#define BK 32
__global__ __launch_bounds__(256) void gemm64_kernel(const float* __restrict__ X,
                                                     const float* __restrict__ W,
                                                     float* __restrict__ Hout,
                                                     int M, int K) {
    __shared__ float Xs[BK][BM + 1];
    __shared__ float Ws[BK][BN];

    const int tid = threadIdx.x;
    const int block_row = blockIdx.x * BM;
    const int tx = tid & 15;
    const int ty = tid >> 4;

    float acc[4][4] = {{0.f}};

    for (int kb = 0; kb < K; kb += BK) {
#pragma unroll
        for (int i = 0; i < 8; ++i) {
            int idx = tid + i * 256;
            int r   = idx >> 5;
            int kk  = idx & (BK - 1);
            int gr  = block_row + r;
            float v = 0.f;
            if (gr < M) v = X[(size_t)gr * K + kb + kk];
            Xs[kk][r] = v;
        }
#pragma unroll
        for (int i = 0; i < 8; ++i) {
            int idx = tid + i * 256;
            int kk  = idx >> 6;
            int c   = idx & (BN - 1);
            Ws[kk][c] = W[(size_t)(kb + kk) * BN + c];
        }
        __syncthreads();

#pragma unroll
        for (int kk = 0; kk < BK; ++kk) {
            float xr[4], wc[4];
#pragma unroll
            for (int i = 0; i < 4; ++i) xr[i] = Xs[kk][ty * 4 + i];
#pragma unroll
            for (int j = 0; j < 4; ++j) wc[j] = Ws[kk][tx * 4 + j];
#pragma unroll
            for (int i = 0; i < 4; ++i)
#pragma unroll
                for (int j = 0; j < 4; ++j)
                    acc[i][j] += xr[i] * wc[j];
        }
        __syncthreads();
    }

#pragma unroll
    for (int i = 0; i < 4; ++i) {
        int gr = block_row + ty * 4 + i;
        if (gr < M) {
#pragma unroll
            for (int j = 0; j < 4; ++j)
                Hout[(size_t)gr * H + tx * 4 + j] = acc[i][j];
        }
    }
}

// ---- fused aggregation: selfloop + gather-sum + bias + ELU ----------------
// one wave per dst node; lane = feature. CSR gather, no atomics.
__global__ __launch_bounds__(256) void agg_fused_kernel(const float* __restrict__ h,
                                                        const float* __restrict__ dinv,
                                                        const int* __restrict__ row_ptr,
                                                        const int* __restrict__ csr_src,
                                                        const float* __restrict__ bias,
                                                        float* __restrict__ out, int n) {
    int lane = threadIdx.x & 63;
    int node = blockIdx.x * 4 + (threadIdx.x >> 6);
    if (node >= n) return;
    int r0 = row_ptr[node];
    int r1 = row_ptr[node + 1];
    float di = dinv[node];
    float acc = h[(size_t)node * H + lane] * di * di;  // self-loop

    for (int base = r0; base < r1; base += 64) {
        int cnt = r1 - base;
        if (cnt > 64) cnt = 64;
        // cooperative prefetch of this chunk's src ids + norms (coalesced)
        int j = base + (lane < cnt ? lane : cnt - 1);
        int sj = csr_src[j];
        float nj = dinv[sj] * di;
#pragma unroll 4
        for (int t = 0; t < cnt; ++t) {
            int s    = __shfl(sj, t, 64);
            float nr = __shfl(nj, t, 64);
            acc += h[(size_t)s * H + lane] * nr;
        }
    }
    float v = acc + bias[lane];
    out[(size_t)node * H + lane] = v > 0.f ? v : (expf(v) - 1.0f);
}

// ---- final FC: out[n,c] = [x1|x2][n,:] @ Wfc + bfc ------------------------
__global__ __launch_bounds__(256) void fc_kernel(const float* __restrict__ x1,
                                                 const float* __restrict__ x2,
                                                 const float* __restrict__ Wfc,
                                                 const float* __restrict__ bfc,
                                                 float* __restrict__ out, int n) {
    int lane = threadIdx.x & 63;
    int node = blockIdx.x * 4 + (threadIdx.x >> 6);
    if (node >= n) return;
    float v1 = x1[(size_t)node * H + lane];
    float v2 = x2[(size_t)node * H + lane];
    float a[4];
#pragma unroll
    for (int c = 0; c < 4; ++c)
        a[c] = v1 * Wfc[lane * 4 + c] + v2 * Wfc[(H + lane) * 4 + c];
#pragma unroll
    for (int off = 32; off > 0; off >>= 1) {
#pragma unroll
        for (int c = 0; c < 4; ++c)
            a[c] += __shfl_down(a[c], off, 64);
    }
    if (lane == 0) {
#pragma unroll
        for (int c = 0; c < 4; ++c)
            out[(size_t)node * 4 + c] = a[c] + bfc[c];
    }
}

// ---------------------------------------------------------------------------
extern "C" void kernel_launch(void* const* d_in, const int* in_sizes, int n_in,
                              void* d_out, int out_size, void* d_ws, size_t ws_size,
                              hipStream_t stream) {
    const float* x_omic1 = (const float*)d_in[0];
    const float* x_omic2 = (const float*)d_in[1];
    const int*   eidx    = (const int*)d_in[2];
    const float* W1a = (const float*)d_in[3];
    const float* b1a = (const float*)d_in[4];
    const float* W2a = (const float*)d_in[5];
    const float* b2a = (const float*)d_in[6];
    const float* W1b = (const float*)d_in[7];
    const float* b1b = (const float*)d_in[8];
    const float* W2b = (const float*)d_in[9];
    const float* b2b = (const float*)d_in[10];
    const float* Wfc = (const float*)d_in[11];
    const float* bfc = (const float*)d_in[12];
    float* out = (float*)d_out;

    const int D1 = 512, D2 = 256;
    const int N = in_sizes[0] / D1;
    const int E = in_sizes[2] / 2;
    const int* src = eidx;
    const int* dst = eidx + E;

    const int nblocks_scan = ceil_div(N, 256);  // <= 512 required by scan_top

    // workspace layout (4B elements), offsets rounded up to 16B:
    size_t off = 0;
    auto alloc = [&](size_t elems) { size_t o = off; off += (elems + 3) & ~(size_t)3; return o; };
    float* base_f = (float*)d_ws;
    int*   base_i = (int*)d_ws;
    float* dinv     = base_f + alloc(N);
    int*   deg      = base_i + alloc(N);       // reused as cursor after scan
    int*   row_ptr  = base_i + alloc(N + 1);
    int*   bsums    = base_i + alloc(1024);
    int*   csr_src  = base_i + alloc(E);
    float* bufA     = base_f + alloc((size_t)N * H);
    float* bufB     = base_f + alloc((size_t)N * H);
    float* bufC     = base_f + alloc((size_t)N * H);
    int*   cursor   = deg;

    const int n64 = N * H;
    dim3 blk(256);
    dim3 grid_e(ceil_div(E, 256));
    dim3 grid_n(ceil_div(N, 256));
    dim3 grid_node(ceil_div(N, 4));
    dim3 grid_gemm(ceil_div(N, BM));

    // ---- CSR build + dinv ----
    hipMemsetAsync(deg, 0, (size_t)N * sizeof(int), stream);
    deg_kernel<<<grid_e, blk, 0, stream>>>(dst, deg, E);
    dinv_kernel<<<grid_n, blk, 0, stream>>>(deg, dinv, N);
    scan_block_kernel<<<nblocks_scan, blk, 0, stream>>>(deg, row_ptr, bsums, N);
    scan_top_kernel<<<1, 512, 0, stream>>>(bsums, nblocks_scan);
    scan_add_kernel<<<grid_n, blk, 0, stream>>>(row_ptr, bsums, cursor, N, E);
    scatter_kernel<<<grid_e, blk, 0, stream>>>(src, dst, cursor, csr_src, E);

    // ---- branch 1: omic1 ----
    gemm64_kernel<<<grid_gemm, blk, 0, stream>>>(x_omic1, W1a, bufA, N, D1);
    agg_fused_kernel<<<grid_node, blk, 0, stream>>>(bufA, dinv, row_ptr, csr_src, b1a, bufB, N);
    gemm64_kernel<<<grid_gemm, blk, 0, stream>>>(bufB, W2a, bufA, N, H);
    agg_fused_kernel<<<grid_node, blk, 0, stream>>>(bufA, dinv, row_ptr, csr_src, b2a, bufC, N);  // x1

    // ---- branch 2: omic2 ----
    gemm64_kernel<<<grid_gemm, blk, 0, stream>>>(x_omic2, W1b, bufA, N, D2);
    agg_fused_kernel<<<grid_node, blk, 0, stream>>>(bufA, dinv, row_ptr, csr_src, b1b, bufB, N);
    gemm64_kernel<<<grid_gemm, blk, 0, stream>>>(bufB, W2b, bufA, N, H);
    agg_fused_kernel<<<grid_node, blk, 0, stream>>>(bufA, dinv, row_ptr, csr_src, b2b, bufB, N);  // x2

    // ---- FC head ----
    fc_kernel<<<grid_node, blk, 0, stream>>>(bufC, bufB, Wfc, bfc, out, N);
}

// Round 3
// 1035.274 us; speedup vs baseline: 2.1557x; 1.3123x over previous
//
#include <hip/hip_runtime.h>
#include <hip/hip_bf16.h>
#include <math.h>

// ---------------------------------------------------------------------------
// MoGCN: two 2-layer GCN branches (H=64) + concat + FC(128->4), fp32.
// Round 2:
//   - GEMM: BM=128 tile, 8x4 micro-tile, b128-aligned LDS, float4 loads
//   - aggregation: paired (both branches, same graph) gather kernel,
//     csr_norm precomputed at scatter; falls back to unpaired if ws is tight
// ---------------------------------------------------------------------------

#define H 64

static inline int ceil_div(int a, int b) { return (a + b - 1) / b; }

// ---- degree (int histogram over dst) --------------------------------------
__global__ __launch_bounds__(256) void deg_kernel(const int* __restrict__ dst,
                                                  int* __restrict__ deg, int E) {
    int e = blockIdx.x * 256 + threadIdx.x;
    if (e < E) atomicAdd(&deg[dst[e]], 1);
}

__global__ __launch_bounds__(256) void dinv_kernel(const int* __restrict__ deg,
                                                   float* __restrict__ dinv, int n) {
    int i = blockIdx.x * 256 + threadIdx.x;
    if (i < n) dinv[i] = rsqrtf((float)deg[i] + 1.0f);  // +1 = self loop
}

// ---- exclusive scan of deg -> row_ptr (3-kernel hierarchical) -------------
__global__ __launch_bounds__(256) void scan_block_kernel(const int* __restrict__ deg,
                                                         int* __restrict__ row_partial,
                                                         int* __restrict__ blocksums,
                                                         int n) {
    __shared__ int s[256];
    int i = blockIdx.x * 256 + threadIdx.x;
    int v = (i < n) ? deg[i] : 0;
    s[threadIdx.x] = v;
    __syncthreads();
#pragma unroll
    for (int off = 1; off < 256; off <<= 1) {
        int t = (threadIdx.x >= off) ? s[threadIdx.x - off] : 0;
        __syncthreads();
        s[threadIdx.x] += t;
        __syncthreads();
    }
    if (i < n) row_partial[i] = s[threadIdx.x] - v;  // exclusive
    if (threadIdx.x == 255) blocksums[blockIdx.x] = s[255];
}

__global__ __launch_bounds__(512) void scan_top_kernel(int* __restrict__ blocksums,
                                                       int nb) {
    __shared__ int s[512];
    int v = (threadIdx.x < (unsigned)nb) ? blocksums[threadIdx.x] : 0;
    s[threadIdx.x] = v;
    __syncthreads();
#pragma unroll
    for (int off = 1; off < 512; off <<= 1) {
        int t = (threadIdx.x >= off) ? s[threadIdx.x - off] : 0;
        __syncthreads();
        s[threadIdx.x] += t;
        __syncthreads();
    }
    if (threadIdx.x < (unsigned)nb) blocksums[threadIdx.x] = s[threadIdx.x] - v;
}

__global__ __launch_bounds__(256) void scan_add_kernel(int* __restrict__ row_ptr,
                                                       const int* __restrict__ blocksums,
                                                       int* __restrict__ cursor,
                                                       int n, int E) {
    int i = blockIdx.x * 256 + threadIdx.x;
    if (i < n) {
        int v = row_ptr[i] + blocksums[blockIdx.x];
        row_ptr[i] = v;
        cursor[i] = v;
    }
    if (i == 0) row_ptr[n] = E;
}

// ---- scatter edges into CSR order, with precomputed edge norms ------------
__global__ __launch_bounds__(256) void scatter_kernel(const int* __restrict__ src,
                                                      const int* __restrict__ dst,
                                                      const float* __restrict__ dinv,
                                                      int* __restrict__ cursor,
                                                      int* __restrict__ csr_src,
                                                      float* __restrict__ csr_norm,
                                                      int E) {
    int e = blockIdx.x * 256 + threadIdx.x;
    if (e >= E) return;
    int s = src[e];
    int d = dst[e];
    int pos = atomicAdd(&cursor[d], 1);
    csr_src[pos] = s;
    csr_norm[pos] = dinv[s] * dinv[d];
}

// ---- GEMM: Hout[M,64] = X[M,K] @ W[K,64] ----------------------------------
// BM=128, BN=64, BK=32; 256 threads; 8x4 register micro-tile per thread.
// b128-aligned LDS reads (pad +4), float4 global loads/stores.
// In-place safe when K==H==64 (each block reads only its own rows, stores
// after the final barrier; the tail clamp only re-reads the block's own row).
#define BM 128
#define BN 64
#define BK 32
__global__ __launch_bounds__(256) void gemm_kernel(const float* __restrict__ X,
                                                   const float* __restrict__ W,
                                                   float* __restrict__ Hout,
                                                   int M, int K) {
    __shared__ float Xs[BK][BM + 4];  // rows 132 floats = 528B, 16B-aligned
    __shared__ float Ws[BK][BN];

    const int tid = threadIdx.x;
    const int block_row = blockIdx.x * BM;
    const int tx = tid & 15;   // col group: 16 groups of 4 cols
    const int ty = tid >> 4;   // row group: 16 groups of 8 rows

    float acc[8][4] = {{0.f}};

    for (int kb = 0; kb < K; kb += BK) {
        // X tile: 128 rows x 32 k = 1024 float4, 4 per thread, coalesced
#pragma unroll
        for (int i = 0; i < 4; ++i) {
            int chunk = tid + i * 256;       // 0..1023
            int r  = chunk >> 3;             // 0..127
            int k4 = (chunk & 7) * 4;
            int gr = block_row + r;
            if (gr >= M) gr = M - 1;
            const float4 v = *(const float4*)&X[(size_t)gr * K + kb + k4];
            Xs[k4 + 0][r] = v.x;
            Xs[k4 + 1][r] = v.y;
            Xs[k4 + 2][r] = v.z;
            Xs[k4 + 3][r] = v.w;
        }
        // W tile: 32 k x 64 n = 512 float4, 2 per thread
#pragma unroll
        for (int i = 0; i < 2; ++i) {
            int chunk = tid + i * 256;       // 0..511
            int kk = chunk >> 4;
            int c4 = (chunk & 15) * 4;
            *(float4*)&Ws[kk][c4] = *(const float4*)&W[(size_t)(kb + kk) * BN + c4];
        }
        __syncthreads();

#pragma unroll
        for (int kk = 0; kk < BK; ++kk) {
            float xr[8], wc[4];
            *(float4*)&xr[0] = *(const float4*)&Xs[kk][ty * 8];
            *(float4*)&xr[4] = *(const float4*)&Xs[kk][ty * 8 + 4];
            *(float4*)&wc[0] = *(const float4*)&Ws[kk][tx * 4];
#pragma unroll
            for (int i = 0; i < 8; ++i)
#pragma unroll
                for (int j = 0; j < 4; ++j)
                    acc[i][j] += xr[i] * wc[j];
        }
        __syncthreads();
    }

#pragma unroll
    for (int i = 0; i < 8; ++i) {
        int gr = block_row + ty * 8 + i;
        if (gr < M) {
            float4 v = make_float4(acc[i][0], acc[i][1], acc[i][2], acc[i][3]);
            *(float4*)&Hout[(size_t)gr * H + tx * 4] = v;
        }
    }
}

// ---- fused aggregation (optionally dual-branch): selfloop+gather+bias+ELU -
// one wave per dst node; lane = feature. CSR gather, no atomics.
__global__ __launch_bounds__(256) void agg2_kernel(const float* __restrict__ h1,
                                                   const float* __restrict__ h2,
                                                   const float* __restrict__ dinv,
                                                   const int* __restrict__ row_ptr,
                                                   const int* __restrict__ csr_src,
                                                   const float* __restrict__ csr_norm,
                                                   const float* __restrict__ b1,
                                                   const float* __restrict__ b2,
                                                   float* __restrict__ o1,
                                                   float* __restrict__ o2, int n) {
    int lane = threadIdx.x & 63;
    int node = blockIdx.x * 4 + (threadIdx.x >> 6);
    if (node >= n) return;
    int r0 = row_ptr[node];
    int r1 = row_ptr[node + 1];
    float di = dinv[node];
    float di2 = di * di;
    size_t nb = (size_t)node * H + lane;
    const bool dual = (h2 != nullptr);   // wave-uniform
    float acc1 = h1[nb] * di2;
    float acc2 = dual ? h2[nb] * di2 : 0.f;

    for (int base = r0; base < r1; base += 64) {
        int cnt = r1 - base;
        if (cnt > 64) cnt = 64;
        int j = base + (lane < cnt ? lane : cnt - 1);
        int sj = csr_src[j];
        float nj = csr_norm[j];
#pragma unroll 4
        for (int t = 0; t < cnt; ++t) {
            int s    = __shfl(sj, t, 64);
            float nr = __shfl(nj, t, 64);
            size_t sb = (size_t)s * H + lane;
            acc1 += h1[sb] * nr;
            if (dual) acc2 += h2[sb] * nr;
        }
    }
    float v1 = acc1 + b1[lane];
    o1[nb] = v1 > 0.f ? v1 : (expf(v1) - 1.0f);
    if (dual) {
        float v2 = acc2 + b2[lane];
        o2[nb] = v2 > 0.f ? v2 : (expf(v2) - 1.0f);
    }
}

// ---- final FC: out[n,c] = [x1|x2][n,:] @ Wfc + bfc ------------------------
__global__ __launch_bounds__(256) void fc_kernel(const float* __restrict__ x1,
                                                 const float* __restrict__ x2,
                                                 const float* __restrict__ Wfc,
                                                 const float* __restrict__ bfc,
                                                 float* __restrict__ out, int n) {
    int lane = threadIdx.x & 63;
    int node = blockIdx.x * 4 + (threadIdx.x >> 6);
    if (node >= n) return;
    float v1 = x1[(size_t)node * H + lane];
    float v2 = x2[(size_t)node * H + lane];
    float a[4];
#pragma unroll
    for (int c = 0; c < 4; ++c)
        a[c] = v1 * Wfc[lane * 4 + c] + v2 * Wfc[(H + lane) * 4 + c];
#pragma unroll
    for (int off = 32; off > 0; off >>= 1) {
#pragma unroll
        for (int c = 0; c < 4; ++c)
            a[c] += __shfl_down(a[c], off, 64);
    }
    if (lane == 0) {
#pragma unroll
        for (int c = 0; c < 4; ++c)
            out[(size_t)node * 4 + c] = a[c] + bfc[c];
    }
}

// ---------------------------------------------------------------------------
extern "C" void kernel_launch(void* const* d_in, const int* in_sizes, int n_in,
                              void* d_out, int out_size, void* d_ws, size_t ws_size,
                              hipStream_t stream) {
    const float* x_omic1 = (const float*)d_in[0];
    const float* x_omic2 = (const float*)d_in[1];
    const int*   eidx    = (const int*)d_in[2];
    const float* W1a = (const float*)d_in[3];
    const float* b1a = (const float*)d_in[4];
    const float* W2a = (const float*)d_in[5];
    const float* b2a = (const float*)d_in[6];
    const float* W1b = (const float*)d_in[7];
    const float* b1b = (const float*)d_in[8];
    const float* W2b = (const float*)d_in[9];
    const float* b2b = (const float*)d_in[10];
    const float* Wfc = (const float*)d_in[11];
    const float* bfc = (const float*)d_in[12];
    float* out = (float*)d_out;

    const int D1 = 512, D2 = 256;
    const int N = in_sizes[0] / D1;
    const int E = in_sizes[2] / 2;
    const int* src = eidx;
    const int* dst = eidx + E;

    const int nblocks_scan = ceil_div(N, 256);  // <= 512 required by scan_top

    // workspace layout (4B elements), offsets rounded up to 16B:
    size_t off = 0;
    auto alloc = [&](size_t elems) { size_t o = off; off += (elems + 3) & ~(size_t)3; return o; };
    float* base_f = (float*)d_ws;
    int*   base_i = (int*)d_ws;
    float* dinv     = base_f + alloc(N);
    int*   deg      = base_i + alloc(N);       // reused as cursor after scan
    int*   row_ptr  = base_i + alloc(N + 1);
    int*   bsums    = base_i + alloc(1024);
    int*   csr_src  = base_i + alloc(E);
    float* csr_norm = base_f + alloc(E);
    float* bufA     = base_f + alloc((size_t)N * H);
    float* bufB     = base_f + alloc((size_t)N * H);
    float* bufC     = base_f + alloc((size_t)N * H);
    size_t need3 = (off + (size_t)N * H) * 4;          // through bufC... + bufD check below
    float* bufD     = base_f + alloc((size_t)N * H);
    size_t need4 = off * 4;
    int*   cursor   = deg;
    const bool paired = (ws_size >= need4);
    (void)need3;

    dim3 blk(256);
    dim3 grid_e(ceil_div(E, 256));
    dim3 grid_n(ceil_div(N, 256));
    dim3 grid_node(ceil_div(N, 4));
    dim3 grid_gemm(ceil_div(N, BM));

    // ---- CSR build + dinv + edge norms ----
    hipMemsetAsync(deg, 0, (size_t)N * sizeof(int), stream);
    deg_kernel<<<grid_e, blk, 0, stream>>>(dst, deg, E);
    dinv_kernel<<<grid_n, blk, 0, stream>>>(deg, dinv, N);
    scan_block_kernel<<<nblocks_scan, blk, 0, stream>>>(deg, row_ptr, bsums, N);
    scan_top_kernel<<<1, 512, 0, stream>>>(bsums, nblocks_scan);
    scan_add_kernel<<<grid_n, blk, 0, stream>>>(row_ptr, bsums, cursor, N, E);
    scatter_kernel<<<grid_e, blk, 0, stream>>>(src, dst, dinv, cursor, csr_src, csr_norm, E);

    if (paired) {
        // layer 1, both branches
        gemm_kernel<<<grid_gemm, blk, 0, stream>>>(x_omic1, W1a, bufA, N, D1);
        gemm_kernel<<<grid_gemm, blk, 0, stream>>>(x_omic2, W1b, bufB, N, D2);
        agg2_kernel<<<grid_node, blk, 0, stream>>>(bufA, bufB, dinv, row_ptr, csr_src,
                                                   csr_norm, b1a, b1b, bufC, bufD, N);
        // layer 2, both branches (in-place GEMM, K=64)
        gemm_kernel<<<grid_gemm, blk, 0, stream>>>(bufC, W2a, bufC, N, H);
        gemm_kernel<<<grid_gemm, blk, 0, stream>>>(bufD, W2b, bufD, N, H);
        agg2_kernel<<<grid_node, blk, 0, stream>>>(bufC, bufD, dinv, row_ptr, csr_src,
                                                   csr_norm, b2a, b2b, bufA, bufB, N);
        fc_kernel<<<grid_node, blk, 0, stream>>>(bufA, bufB, Wfc, bfc, out, N);
    } else {
        // unpaired fallback, 3 buffers
        gemm_kernel<<<grid_gemm, blk, 0, stream>>>(x_omic1, W1a, bufA, N, D1);
        agg2_kernel<<<grid_node, blk, 0, stream>>>(bufA, nullptr, dinv, row_ptr, csr_src,
                                                   csr_norm, b1a, nullptr, bufB, nullptr, N);
        gemm_kernel<<<grid_gemm, blk, 0, stream>>>(bufB, W2a, bufA, N, H);
        agg2_kernel<<<grid_node, blk, 0, stream>>>(bufA, nullptr, dinv, row_ptr, csr_src,
                                                   csr_norm, b2a, nullptr, bufC, nullptr, N);
        gemm_kernel<<<grid_gemm, blk, 0, stream>>>(x_omic2, W1b, bufA, N, D2);
        agg2_kernel<<<grid_node, blk, 0, stream>>>(bufA, nullptr, dinv, row_ptr, csr_src,
                                                   csr_norm, b1b, nullptr, bufB, nullptr, N);
        gemm_kernel<<<grid_gemm, blk, 0, stream>>>(bufB, W2b, bufA, N, H);
        agg2_kernel<<<grid_node, blk, 0, stream>>>(bufA, nullptr, dinv, row_ptr, csr_src,
                                                   csr_norm, b2b, nullptr, bufB, nullptr, N);
        fc_kernel<<<grid_node, blk, 0, stream>>>(bufC, bufB, Wfc, bfc, out, N);
    }
}

// Round 4
// 861.096 us; speedup vs baseline: 2.5917x; 1.2023x over previous
//
#include <hip/hip_runtime.h>
#include <hip/hip_bf16.h>
#include <math.h>

// ---------------------------------------------------------------------------
// MoGCN: two 2-layer GCN branches (H=64) + concat + FC(128->4), fp32 in/out.
// Round 3:
//   - GEMM outputs bf16 (RNE); aggregation gathers bf16 rows (128 B/edge,
//     halves the L2-miss-bound gather traffic), accumulates fp32
//   - agg: 2 dst nodes per wave (lane = uint = 2 bf16 feats), dual-branch
//   - FC head fused into the second aggregation (no x1/x2 round-trip)
// ---------------------------------------------------------------------------

#define H 64

static inline int ceil_div(int a, int b) { return (a + b - 1) / b; }

__device__ inline unsigned short f2bf_rne(float f) {
    unsigned u = __float_as_uint(f);
    u += 0x7fffu + ((u >> 16) & 1u);
    return (unsigned short)(u >> 16);
}
__device__ inline float2 bf2x(unsigned w) {  // uint -> two floats (cols 2l, 2l+1)
    float2 r;
    r.x = __uint_as_float(w << 16);
    r.y = __uint_as_float(w & 0xffff0000u);
    return r;
}

// ---- degree (int histogram over dst) --------------------------------------
__global__ __launch_bounds__(256) void deg_kernel(const int* __restrict__ dst,
                                                  int* __restrict__ deg, int E) {
    int e = blockIdx.x * 256 + threadIdx.x;
    if (e < E) atomicAdd(&deg[dst[e]], 1);
}

__global__ __launch_bounds__(256) void dinv_kernel(const int* __restrict__ deg,
                                                   float* __restrict__ dinv, int n) {
    int i = blockIdx.x * 256 + threadIdx.x;
    if (i < n) dinv[i] = rsqrtf((float)deg[i] + 1.0f);  // +1 = self loop
}

// ---- exclusive scan of deg -> row_ptr (3-kernel hierarchical) -------------
__global__ __launch_bounds__(256) void scan_block_kernel(const int* __restrict__ deg,
                                                         int* __restrict__ row_partial,
                                                         int* __restrict__ blocksums,
                                                         int n) {
    __shared__ int s[256];
    int i = blockIdx.x * 256 + threadIdx.x;
    int v = (i < n) ? deg[i] : 0;
    s[threadIdx.x] = v;
    __syncthreads();
#pragma unroll
    for (int off = 1; off < 256; off <<= 1) {
        int t = (threadIdx.x >= off) ? s[threadIdx.x - off] : 0;
        __syncthreads();
        s[threadIdx.x] += t;
        __syncthreads();
    }
    if (i < n) row_partial[i] = s[threadIdx.x] - v;  // exclusive
    if (threadIdx.x == 255) blocksums[blockIdx.x] = s[255];
}

__global__ __launch_bounds__(512) void scan_top_kernel(int* __restrict__ blocksums,
                                                       int nb) {
    __shared__ int s[512];
    int v = (threadIdx.x < (unsigned)nb) ? blocksums[threadIdx.x] : 0;
    s[threadIdx.x] = v;
    __syncthreads();
#pragma unroll
    for (int off = 1; off < 512; off <<= 1) {
        int t = (threadIdx.x >= off) ? s[threadIdx.x - off] : 0;
        __syncthreads();
        s[threadIdx.x] += t;
        __syncthreads();
    }
    if (threadIdx.x < (unsigned)nb) blocksums[threadIdx.x] = s[threadIdx.x] - v;
}

__global__ __launch_bounds__(256) void scan_add_kernel(int* __restrict__ row_ptr,
                                                       const int* __restrict__ blocksums,
                                                       int* __restrict__ cursor,
                                                       int n, int E) {
    int i = blockIdx.x * 256 + threadIdx.x;
    if (i < n) {
        int v = row_ptr[i] + blocksums[blockIdx.x];
        row_ptr[i] = v;
        cursor[i] = v;
    }
    if (i == 0) row_ptr[n] = E;
}

// ---- scatter edges into CSR order, with precomputed edge norms ------------
__global__ __launch_bounds__(256) void scatter_kernel(const int* __restrict__ src,
                                                      const int* __restrict__ dst,
                                                      const float* __restrict__ dinv,
                                                      int* __restrict__ cursor,
                                                      int* __restrict__ csr_src,
                                                      float* __restrict__ csr_norm,
                                                      int E) {
    int e = blockIdx.x * 256 + threadIdx.x;
    if (e >= E) return;
    int s = src[e];
    int d = dst[e];
    int pos = atomicAdd(&cursor[d], 1);
    csr_src[pos] = s;
    csr_norm[pos] = dinv[s] * dinv[d];
}

// ---- GEMM: Hout_bf16[M,64] = X[M,K] @ W[K,64] -----------------------------
// BM=128, BN=64, BK=32; 256 threads; 8x4 micro-tile; bf16 (RNE) output.
#define BM 128
#define BN 64
#define BK 32
__global__ __launch_bounds__(256) void gemm_bf_kernel(const float* __restrict__ X,
                                                      const float* __restrict__ W,
                                                      unsigned short* __restrict__ Hout,
                                                      int M, int K) {
    __shared__ float Xs[BK][BM + 4];
    __shared__ float Ws[BK][BN];

    const int tid = threadIdx.x;
    const int block_row = blockIdx.x * BM;
    const int tx = tid & 15;   // 16 groups of 4 cols
    const int ty = tid >> 4;   // 16 groups of 8 rows

    float acc[8][4] = {{0.f}};

    for (int kb = 0; kb < K; kb += BK) {
#pragma unroll
        for (int i = 0; i < 4; ++i) {
            int chunk = tid + i * 256;       // 0..1023
            int r  = chunk >> 3;             // 0..127
            int k4 = (chunk & 7) * 4;
            int gr = block_row + r;
            if (gr >= M) gr = M - 1;
            const float4 v = *(const float4*)&X[(size_t)gr * K + kb + k4];
            Xs[k4 + 0][r] = v.x;
            Xs[k4 + 1][r] = v.y;
            Xs[k4 + 2][r] = v.z;
            Xs[k4 + 3][r] = v.w;
        }
#pragma unroll
        for (int i = 0; i < 2; ++i) {
            int chunk = tid + i * 256;       // 0..511
            int kk = chunk >> 4;
            int c4 = (chunk & 15) * 4;
            *(float4*)&Ws[kk][c4] = *(const float4*)&W[(size_t)(kb + kk) * BN + c4];
        }
        __syncthreads();

#pragma unroll
        for (int kk = 0; kk < BK; ++kk) {
            float xr[8], wc[4];
            *(float4*)&xr[0] = *(const float4*)&Xs[kk][ty * 8];
            *(float4*)&xr[4] = *(const float4*)&Xs[kk][ty * 8 + 4];
            *(float4*)&wc[0] = *(const float4*)&Ws[kk][tx * 4];
#pragma unroll
            for (int i = 0; i < 8; ++i)
#pragma unroll
                for (int j = 0; j < 4; ++j)
                    acc[i][j] += xr[i] * wc[j];
        }
        __syncthreads();
    }

#pragma unroll
    for (int i = 0; i < 8; ++i) {
        int gr = block_row + ty * 8 + i;
        if (gr < M) {
            ushort4 v;
            v.x = f2bf_rne(acc[i][0]);
            v.y = f2bf_rne(acc[i][1]);
            v.z = f2bf_rne(acc[i][2]);
            v.w = f2bf_rne(acc[i][3]);
            *(ushort4*)&Hout[(size_t)gr * H + tx * 4] = v;
        }
    }
}

// ---- fused dual-branch aggregation: selfloop+gather+bias+ELU [+FC] --------
// 2 dst nodes per wave: lanes 0-31 -> node a, 32-63 -> node b.
// lane l holds features (2l, 2l+1) as one uint (2 bf16); fp32 accumulate.
// If Wfc != nullptr: reduce to 4 classes and write `out` (no o1/o2 stores).
__global__ __launch_bounds__(256) void agg2_kernel(const unsigned* __restrict__ h1,
                                                   const unsigned* __restrict__ h2,
                                                   const float* __restrict__ dinv,
                                                   const int* __restrict__ row_ptr,
                                                   const int* __restrict__ csr_src,
                                                   const float* __restrict__ csr_norm,
                                                   const float* __restrict__ b1,
                                                   const float* __restrict__ b2,
                                                   float2* __restrict__ o1,
                                                   float2* __restrict__ o2,
                                                   const float* __restrict__ Wfc,
                                                   const float* __restrict__ bfc,
                                                   float* __restrict__ out, int n) {
    const int tid  = threadIdx.x;
    const int lane = tid & 63;
    const int wave = tid >> 6;
    const int half = lane >> 5;
    const int l    = lane & 31;
    const int hb   = half << 5;
    const int node = blockIdx.x * 8 + wave * 2 + half;
    const bool active = (node < n);

    int r0 = 0, r1 = 0;
    float di = 0.f;
    if (active) { r0 = row_ptr[node]; r1 = row_ptr[node + 1]; di = dinv[node]; }
    const float di2 = di * di;
    const int rowoff = node * 32 + l;

    float2 acc1 = make_float2(0.f, 0.f), acc2 = make_float2(0.f, 0.f);
    if (active) {
        float2 s1 = bf2x(h1[rowoff]);
        float2 s2 = bf2x(h2[rowoff]);
        acc1.x = s1.x * di2; acc1.y = s1.y * di2;
        acc2.x = s2.x * di2; acc2.y = s2.y * di2;
    }

    for (int base = r0; base < r1; base += 32) {
        int cnt = r1 - base;
        if (cnt > 32) cnt = 32;
        int j = base + (l < cnt ? l : cnt - 1);   // coalesced chunk prefetch
        int sj = csr_src[j];
        float nj = csr_norm[j];
#pragma unroll 4
        for (int t = 0; t < cnt; ++t) {
            int s    = __shfl(sj, hb | t, 64);
            float nr = __shfl(nj, hb | t, 64);
            float2 g1 = bf2x(h1[s * 32 + l]);
            float2 g2 = bf2x(h2[s * 32 + l]);
            acc1.x = fmaf(g1.x, nr, acc1.x);
            acc1.y = fmaf(g1.y, nr, acc1.y);
            acc2.x = fmaf(g2.x, nr, acc2.x);
            acc2.y = fmaf(g2.y, nr, acc2.y);
        }
    }

    // bias + ELU
    float2 bv1 = ((const float2*)b1)[l];
    float2 bv2 = ((const float2*)b2)[l];
    float2 v1, v2;
    v1.x = acc1.x + bv1.x; v1.y = acc1.y + bv1.y;
    v2.x = acc2.x + bv2.x; v2.y = acc2.y + bv2.y;
    v1.x = v1.x > 0.f ? v1.x : (expf(v1.x) - 1.f);
    v1.y = v1.y > 0.f ? v1.y : (expf(v1.y) - 1.f);
    v2.x = v2.x > 0.f ? v2.x : (expf(v2.x) - 1.f);
    v2.y = v2.y > 0.f ? v2.y : (expf(v2.y) - 1.f);

    if (Wfc == nullptr) {
        if (active) { o1[rowoff] = v1; o2[rowoff] = v2; }
        return;
    }

    // fused FC: out[node,c] = sum_k x1[k]Wfc[k,c] + x2[k]Wfc[64+k,c] + bfc[c]
    const float* Wp1 = &Wfc[(2 * l) * 4];         // rows 2l, 2l+1
    const float* Wp2 = &Wfc[(H + 2 * l) * 4];     // rows 64+2l, 64+2l+1
    float a[4];
#pragma unroll
    for (int c = 0; c < 4; ++c)
        a[c] = v1.x * Wp1[c] + v1.y * Wp1[4 + c] + v2.x * Wp2[c] + v2.y * Wp2[4 + c];
#pragma unroll
    for (int off = 16; off > 0; off >>= 1) {
#pragma unroll
        for (int c = 0; c < 4; ++c)
            a[c] += __shfl_down(a[c], off, 64);   // stays within the half-wave prefix
    }
    if (l == 0 && active) {
#pragma unroll
        for (int c = 0; c < 4; ++c)
            out[(size_t)node * 4 + c] = a[c] + bfc[c];
    }
}

// ---------------------------------------------------------------------------
extern "C" void kernel_launch(void* const* d_in, const int* in_sizes, int n_in,
                              void* d_out, int out_size, void* d_ws, size_t ws_size,
                              hipStream_t stream) {
    const float* x_omic1 = (const float*)d_in[0];
    const float* x_omic2 = (const float*)d_in[1];
    const int*   eidx    = (const int*)d_in[2];
    const float* W1a = (const float*)d_in[3];
    const float* b1a = (const float*)d_in[4];
    const float* W2a = (const float*)d_in[5];
    const float* b2a = (const float*)d_in[6];
    const float* W1b = (const float*)d_in[7];
    const float* b1b = (const float*)d_in[8];
    const float* W2b = (const float*)d_in[9];
    const float* b2b = (const float*)d_in[10];
    const float* Wfc = (const float*)d_in[11];
    const float* bfc = (const float*)d_in[12];
    float* out = (float*)d_out;

    const int D1 = 512, D2 = 256;
    const int N = in_sizes[0] / D1;
    const int E = in_sizes[2] / 2;
    const int* src = eidx;
    const int* dst = eidx + E;

    const int nblocks_scan = ceil_div(N, 256);  // <= 512 required by scan_top

    // workspace layout (4B elements), 16B-aligned chunks
    size_t off = 0;
    auto alloc = [&](size_t elems) { size_t o = off; off += (elems + 3) & ~(size_t)3; return o; };
    float*    base_f = (float*)d_ws;
    int*      base_i = (int*)d_ws;
    unsigned* base_u = (unsigned*)d_ws;
    float*    dinv     = base_f + alloc(N);
    int*      deg      = base_i + alloc(N);      // reused as cursor
    int*      row_ptr  = base_i + alloc(N + 1);
    int*      bsums    = base_i + alloc(1024);
    int*      csr_src  = base_i + alloc(E);
    float*    csr_norm = base_f + alloc(E);
    unsigned* h1bf     = base_u + alloc((size_t)N * 32);  // N x 64 bf16
    unsigned* h2bf     = base_u + alloc((size_t)N * 32);
    float*    x1       = base_f + alloc((size_t)N * H);
    float*    x2       = base_f + alloc((size_t)N * H);
    int*      cursor   = deg;

    dim3 blk(256);
    dim3 grid_e(ceil_div(E, 256));
    dim3 grid_n(ceil_div(N, 256));
    dim3 grid_agg(ceil_div(N, 8));
    dim3 grid_gemm(ceil_div(N, BM));

    // ---- CSR build + dinv + edge norms ----
    hipMemsetAsync(deg, 0, (size_t)N * sizeof(int), stream);
    deg_kernel<<<grid_e, blk, 0, stream>>>(dst, deg, E);
    dinv_kernel<<<grid_n, blk, 0, stream>>>(deg, dinv, N);
    scan_block_kernel<<<nblocks_scan, blk, 0, stream>>>(deg, row_ptr, bsums, N);
    scan_top_kernel<<<1, 512, 0, stream>>>(bsums, nblocks_scan);
    scan_add_kernel<<<grid_n, blk, 0, stream>>>(row_ptr, bsums, cursor, N, E);
    scatter_kernel<<<grid_e, blk, 0, stream>>>(src, dst, dinv, cursor, csr_src, csr_norm, E);

    // ---- layer 1, both branches ----
    gemm_bf_kernel<<<grid_gemm, blk, 0, stream>>>(x_omic1, W1a, (unsigned short*)h1bf, N, D1);
    gemm_bf_kernel<<<grid_gemm, blk, 0, stream>>>(x_omic2, W1b, (unsigned short*)h2bf, N, D2);
    agg2_kernel<<<grid_agg, blk, 0, stream>>>(h1bf, h2bf, dinv, row_ptr, csr_src, csr_norm,
                                              b1a, b1b, (float2*)x1, (float2*)x2,
                                              nullptr, nullptr, nullptr, N);
    // ---- layer 2, both branches + fused FC ----
    gemm_bf_kernel<<<grid_gemm, blk, 0, stream>>>(x1, W2a, (unsigned short*)h1bf, N, H);
    gemm_bf_kernel<<<grid_gemm, blk, 0, stream>>>(x2, W2b, (unsigned short*)h2bf, N, H);
    agg2_kernel<<<grid_agg, blk, 0, stream>>>(h1bf, h2bf, dinv, row_ptr, csr_src, csr_norm,
                                              b2a, b2b, nullptr, nullptr,
                                              Wfc, bfc, out, N);
}

// Round 5
// 843.474 us; speedup vs baseline: 2.6459x; 1.0209x over previous
//
#include <hip/hip_runtime.h>
#include <hip/hip_bf16.h>
#include <math.h>

// ---------------------------------------------------------------------------
// MoGCN: two 2-layer GCN branches (H=64) + concat + FC(128->4), fp32 in/out.
// Round 4:
//   - All GEMMs via MFMA 16x16x32 bf16, LDS-free (A-frags straight from
//     global fp32 rows; B-frags pre-packed in MFMA lane order per call).
//   - Split precision: layer1 A = xhi+xlo, W = Whi+Wlo, 3 MFMAs (bf16x3);
//     layer2 A is exact bf16, W split, 2 MFMAs -> fp32-class GEMM accuracy.
//   - agg outputs packed bf16 (halves write traffic; feeds layer-2 A direct).
// ---------------------------------------------------------------------------

#define H 64

static inline int ceil_div(int a, int b) { return (a + b - 1) / b; }

typedef __attribute__((ext_vector_type(8))) short short8_t;  // 8 bf16
typedef __attribute__((ext_vector_type(4))) float f32x4;

__device__ inline unsigned short f2bf_rne(float f) {
    unsigned u = __float_as_uint(f);
    u += 0x7fffu + ((u >> 16) & 1u);
    return (unsigned short)(u >> 16);
}
__device__ inline unsigned pk_bf(float a, float b) {  // low=a (even col), high=b
    return (unsigned)f2bf_rne(a) | ((unsigned)f2bf_rne(b) << 16);
}
__device__ inline float2 bf2x(unsigned w) {  // low short -> x, high -> y
    float2 r;
    r.x = __uint_as_float(w << 16);
    r.y = __uint_as_float(w & 0xffff0000u);
    return r;
}
union V8 { uint4 u4; unsigned u[4]; short8_t s; };

// ---- degree / dinv --------------------------------------------------------
__global__ __launch_bounds__(256) void deg_kernel(const int* __restrict__ dst,
                                                  int* __restrict__ deg, int E) {
    int e = blockIdx.x * 256 + threadIdx.x;
    if (e < E) atomicAdd(&deg[dst[e]], 1);
}

__global__ __launch_bounds__(256) void dinv_kernel(const int* __restrict__ deg,
                                                   float* __restrict__ dinv, int n) {
    int i = blockIdx.x * 256 + threadIdx.x;
    if (i < n) dinv[i] = rsqrtf((float)deg[i] + 1.0f);  // +1 = self loop
}

// ---- exclusive scan of deg -> row_ptr -------------------------------------
__global__ __launch_bounds__(256) void scan_block_kernel(const int* __restrict__ deg,
                                                         int* __restrict__ row_partial,
                                                         int* __restrict__ blocksums,
                                                         int n) {
    __shared__ int s[256];
    int i = blockIdx.x * 256 + threadIdx.x;
    int v = (i < n) ? deg[i] : 0;
    s[threadIdx.x] = v;
    __syncthreads();
#pragma unroll
    for (int off = 1; off < 256; off <<= 1) {
        int t = (threadIdx.x >= off) ? s[threadIdx.x - off] : 0;
        __syncthreads();
        s[threadIdx.x] += t;
        __syncthreads();
    }
    if (i < n) row_partial[i] = s[threadIdx.x] - v;
    if (threadIdx.x == 255) blocksums[blockIdx.x] = s[255];
}

__global__ __launch_bounds__(512) void scan_top_kernel(int* __restrict__ blocksums,
                                                       int nb) {
    __shared__ int s[512];
    int v = (threadIdx.x < (unsigned)nb) ? blocksums[threadIdx.x] : 0;
    s[threadIdx.x] = v;
    __syncthreads();
#pragma unroll
    for (int off = 1; off < 512; off <<= 1) {
        int t = (threadIdx.x >= off) ? s[threadIdx.x - off] : 0;
        __syncthreads();
        s[threadIdx.x] += t;
        __syncthreads();
    }
    if (threadIdx.x < (unsigned)nb) blocksums[threadIdx.x] = s[threadIdx.x] - v;
}

__global__ __launch_bounds__(256) void scan_add_kernel(int* __restrict__ row_ptr,
                                                       const int* __restrict__ blocksums,
                                                       int* __restrict__ cursor,
                                                       int n, int E) {
    int i = blockIdx.x * 256 + threadIdx.x;
    if (i < n) {
        int v = row_ptr[i] + blocksums[blockIdx.x];
        row_ptr[i] = v;
        cursor[i] = v;
    }
    if (i == 0) row_ptr[n] = E;
}

// ---- scatter edges into CSR order + edge norms ----------------------------
__global__ __launch_bounds__(256) void scatter_kernel(const int* __restrict__ src,
                                                      const int* __restrict__ dst,
                                                      const float* __restrict__ dinv,
                                                      int* __restrict__ cursor,
                                                      int* __restrict__ csr_src,
                                                      float* __restrict__ csr_norm,
                                                      int E) {
    int e = blockIdx.x * 256 + threadIdx.x;
    if (e >= E) return;
    int s = src[e];
    int d = dst[e];
    int pos = atomicAdd(&cursor[d], 1);
    csr_src[pos] = s;
    csr_norm[pos] = dinv[s] * dinv[d];
}

// ---- W fragment pre-pack: W[K][64] fp32 -> hi/lo bf16 MFMA lane order -----
// frag layout (uint4 units): [(kstep*4 + nt)*2 + {0=hi,1=lo}][lane 0..63]
// lane l holds B[k = kstep*32 + (l>>4)*8 + j][n = nt*16 + (l&15)], j=0..7.
__global__ __launch_bounds__(256) void wfrag_kernel(const float* __restrict__ W,
                                                    uint4* __restrict__ frag, int K) {
    int t = blockIdx.x * 256 + threadIdx.x;
    int total = (K >> 5) * 256;
    if (t >= total) return;
    int lane = t & 63, nt = (t >> 6) & 3, ks = t >> 8;
    int nl = lane & 15, q = lane >> 4;
    float hi[8], lo[8];
#pragma unroll
    for (int j = 0; j < 8; ++j) {
        float w = W[(size_t)(ks * 32 + q * 8 + j) * 64 + nt * 16 + nl];
        unsigned hb = f2bf_rne(w);
        float hf = __uint_as_float(((unsigned)hb) << 16);
        hi[j] = hf;
        lo[j] = w - hf;
    }
    V8 vh, vl;
#pragma unroll
    for (int j = 0; j < 4; ++j) {
        vh.u[j] = pk_bf(hi[2 * j], hi[2 * j + 1]);
        vl.u[j] = pk_bf(lo[2 * j], lo[2 * j + 1]);
    }
    size_t base = (size_t)((ks * 4 + nt) * 2) * 64 + lane;
    frag[base] = vh.u4;
    frag[base + 64] = vl.u4;
}

// ---- layer-1 GEMM: Hout_bf16[M,64] = X_fp32[M,K] @ W (bf16x3 split) -------
// 256 thr = 4 waves; wave owns 16 rows x 64 cols (4 MFMA C-tiles). No LDS.
__global__ __launch_bounds__(256) void gemm_l1_kernel(const float* __restrict__ X,
                                                      const uint4* __restrict__ wf,
                                                      unsigned* __restrict__ Hout,
                                                      int M, int K) {
    const int tid = threadIdx.x;
    const int w = tid >> 6, l = tid & 63;
    const int m = l & 15, q = l >> 4;
    const int tile = blockIdx.x * 64 + w * 16;
    int row = tile + m;
    int rowc = row < M ? row : M - 1;
    const float* Xr = X + (size_t)rowc * K;

    f32x4 acc[4];
#pragma unroll
    for (int nt = 0; nt < 4; ++nt) acc[nt] = (f32x4){0.f, 0.f, 0.f, 0.f};

    const int ksteps = K >> 5;
    for (int ks = 0; ks < ksteps; ++ks) {
        const float4 f0 = *(const float4*)&Xr[ks * 32 + q * 8];
        const float4 f1 = *(const float4*)&Xr[ks * 32 + q * 8 + 4];
        float xs[8] = {f0.x, f0.y, f0.z, f0.w, f1.x, f1.y, f1.z, f1.w};
        V8 ah, al;
#pragma unroll
        for (int j = 0; j < 4; ++j) {
            float a = xs[2 * j], b = xs[2 * j + 1];
            unsigned ha = f2bf_rne(a), hb = f2bf_rne(b);
            float fa = __uint_as_float(ha << 16);
            float fb = __uint_as_float(hb << 16);
            ah.u[j] = ha | (hb << 16);
            al.u[j] = pk_bf(a - fa, b - fb);
        }
        const uint4* base = wf + (size_t)(ks * 4) * 2 * 64 + l;
#pragma unroll
        for (int nt = 0; nt < 4; ++nt) {
            V8 bh, bl;
            bh.u4 = base[(size_t)(nt * 2) * 64];
            bl.u4 = base[(size_t)(nt * 2 + 1) * 64];
            acc[nt] = __builtin_amdgcn_mfma_f32_16x16x32_bf16(ah.s, bh.s, acc[nt], 0, 0, 0);
            acc[nt] = __builtin_amdgcn_mfma_f32_16x16x32_bf16(al.s, bh.s, acc[nt], 0, 0, 0);
            acc[nt] = __builtin_amdgcn_mfma_f32_16x16x32_bf16(ah.s, bl.s, acc[nt], 0, 0, 0);
        }
    }

    // C layout: col = l&15, rows = q*4 + i. Pack col pairs via shfl_xor.
    const int rbase = tile + q * 4;
#pragma unroll
    for (int nt = 0; nt < 4; ++nt) {
#pragma unroll
        for (int i = 0; i < 4; ++i) {
            float f = acc[nt][i];
            float fo = __shfl_xor(f, 1, 64);
            int r = rbase + i;
            if (((l & 1) == 0) && r < M)
                Hout[(size_t)r * 32 + nt * 8 + (m >> 1)] = pk_bf(f, fo);
        }
    }
}

// ---- layer-2 GEMM: Hout_bf16[M,64] = X_bf16[M,64] @ W (W split, 2 MFMA) ---
__global__ __launch_bounds__(256) void gemm_l2_kernel(const uint4* __restrict__ Xb,
                                                      const uint4* __restrict__ wf,
                                                      unsigned* __restrict__ Hout,
                                                      int M) {
    const int tid = threadIdx.x;
    const int w = tid >> 6, l = tid & 63;
    const int m = l & 15, q = l >> 4;
    const int tile = blockIdx.x * 64 + w * 16;
    int row = tile + m;
    int rowc = row < M ? row : M - 1;

    f32x4 acc[4];
#pragma unroll
    for (int nt = 0; nt < 4; ++nt) acc[nt] = (f32x4){0.f, 0.f, 0.f, 0.f};

#pragma unroll
    for (int ks = 0; ks < 2; ++ks) {
        V8 av;
        av.u4 = Xb[(size_t)rowc * 8 + ks * 4 + q];   // 8 consecutive bf16 k's
        const uint4* base = wf + (size_t)(ks * 4) * 2 * 64 + l;
#pragma unroll
        for (int nt = 0; nt < 4; ++nt) {
            V8 bh, bl;
            bh.u4 = base[(size_t)(nt * 2) * 64];
            bl.u4 = base[(size_t)(nt * 2 + 1) * 64];
            acc[nt] = __builtin_amdgcn_mfma_f32_16x16x32_bf16(av.s, bh.s, acc[nt], 0, 0, 0);
            acc[nt] = __builtin_amdgcn_mfma_f32_16x16x32_bf16(av.s, bl.s, acc[nt], 0, 0, 0);
        }
    }

    const int rbase = tile + q * 4;
#pragma unroll
    for (int nt = 0; nt < 4; ++nt) {
#pragma unroll
        for (int i = 0; i < 4; ++i) {
            float f = acc[nt][i];
            float fo = __shfl_xor(f, 1, 64);
            int r = rbase + i;
            if (((l & 1) == 0) && r < M)
                Hout[(size_t)r * 32 + nt * 8 + (m >> 1)] = pk_bf(f, fo);
        }
    }
}

// ---- fused dual-branch aggregation: selfloop+gather+bias+ELU [+FC] --------
// 2 dst nodes per wave; lane l holds features (2l,2l+1) as packed bf16.
// o1/o2 (when Wfc==null) are packed-bf16 outputs feeding the layer-2 GEMM.
__global__ __launch_bounds__(256) void agg2_kernel(const unsigned* __restrict__ h1,
                                                   const unsigned* __restrict__ h2,
                                                   const float* __restrict__ dinv,
                                                   const int* __restrict__ row_ptr,
                                                   const int* __restrict__ csr_src,
                                                   const float* __restrict__ csr_norm,
                                                   const float* __restrict__ b1,
                                                   const float* __restrict__ b2,
                                                   unsigned* __restrict__ o1,
                                                   unsigned* __restrict__ o2,
                                                   const float* __restrict__ Wfc,
                                                   const float* __restrict__ bfc,
                                                   float* __restrict__ out, int n) {
    const int tid  = threadIdx.x;
    const int lane = tid & 63;
    const int wave = tid >> 6;
    const int half = lane >> 5;
    const int l    = lane & 31;
    const int hb   = half << 5;
    const int node = blockIdx.x * 8 + wave * 2 + half;
    const bool active = (node < n);

    int r0 = 0, r1 = 0;
    float di = 0.f;
    if (active) { r0 = row_ptr[node]; r1 = row_ptr[node + 1]; di = dinv[node]; }
    const float di2 = di * di;
    const int rowoff = node * 32 + l;

    float2 acc1 = make_float2(0.f, 0.f), acc2 = make_float2(0.f, 0.f);
    if (active) {
        float2 s1 = bf2x(h1[rowoff]);
        float2 s2 = bf2x(h2[rowoff]);
        acc1.x = s1.x * di2; acc1.y = s1.y * di2;
        acc2.x = s2.x * di2; acc2.y = s2.y * di2;
    }

    for (int base = r0; base < r1; base += 32) {
        int cnt = r1 - base;
        if (cnt > 32) cnt = 32;
        int j = base + (l < cnt ? l : cnt - 1);   // coalesced chunk prefetch
        int sj = csr_src[j];
        float nj = csr_norm[j];
#pragma unroll 4
        for (int t = 0; t < cnt; ++t) {
            int s    = __shfl(sj, hb | t, 64);
            float nr = __shfl(nj, hb | t, 64);
            float2 g1 = bf2x(h1[s * 32 + l]);
            float2 g2 = bf2x(h2[s * 32 + l]);
            acc1.x = fmaf(g1.x, nr, acc1.x);
            acc1.y = fmaf(g1.y, nr, acc1.y);
            acc2.x = fmaf(g2.x, nr, acc2.x);
            acc2.y = fmaf(g2.y, nr, acc2.y);
        }
    }

    float2 bv1 = ((const float2*)b1)[l];
    float2 bv2 = ((const float2*)b2)[l];
    float2 v1, v2;
    v1.x = acc1.x + bv1.x; v1.y = acc1.y + bv1.y;
    v2.x = acc2.x + bv2.x; v2.y = acc2.y + bv2.y;
    v1.x = v1.x > 0.f ? v1.x : (expf(v1.x) - 1.f);
    v1.y = v1.y > 0.f ? v1.y : (expf(v1.y) - 1.f);
    v2.x = v2.x > 0.f ? v2.x : (expf(v2.x) - 1.f);
    v2.y = v2.y > 0.f ? v2.y : (expf(v2.y) - 1.f);

    if (Wfc == nullptr) {
        if (active) {
            o1[rowoff] = pk_bf(v1.x, v1.y);
            o2[rowoff] = pk_bf(v2.x, v2.y);
        }
        return;
    }

    // fused FC head
    const float* Wp1 = &Wfc[(2 * l) * 4];
    const float* Wp2 = &Wfc[(H + 2 * l) * 4];
    float a[4];
#pragma unroll
    for (int c = 0; c < 4; ++c)
        a[c] = v1.x * Wp1[c] + v1.y * Wp1[4 + c] + v2.x * Wp2[c] + v2.y * Wp2[4 + c];
#pragma unroll
    for (int off = 16; off > 0; off >>= 1) {
#pragma unroll
        for (int c = 0; c < 4; ++c)
            a[c] += __shfl_down(a[c], off, 64);
    }
    if (l == 0 && active) {
#pragma unroll
        for (int c = 0; c < 4; ++c)
            out[(size_t)node * 4 + c] = a[c] + bfc[c];
    }
}

// ---------------------------------------------------------------------------
extern "C" void kernel_launch(void* const* d_in, const int* in_sizes, int n_in,
                              void* d_out, int out_size, void* d_ws, size_t ws_size,
                              hipStream_t stream) {
    const float* x_omic1 = (const float*)d_in[0];
    const float* x_omic2 = (const float*)d_in[1];
    const int*   eidx    = (const int*)d_in[2];
    const float* W1a = (const float*)d_in[3];
    const float* b1a = (const float*)d_in[4];
    const float* W2a = (const float*)d_in[5];
    const float* b2a = (const float*)d_in[6];
    const float* W1b = (const float*)d_in[7];
    const float* b1b = (const float*)d_in[8];
    const float* W2b = (const float*)d_in[9];
    const float* b2b = (const float*)d_in[10];
    const float* Wfc = (const float*)d_in[11];
    const float* bfc = (const float*)d_in[12];
    float* out = (float*)d_out;

    const int D1 = 512, D2 = 256;
    const int N = in_sizes[0] / D1;
    const int E = in_sizes[2] / 2;
    const int* src = eidx;
    const int* dst = eidx + E;

    const int nblocks_scan = ceil_div(N, 256);

    // workspace layout (4B units, 16B-aligned chunks)
    size_t off = 0;
    auto alloc = [&](size_t elems) { size_t o = off; off += (elems + 3) & ~(size_t)3; return o; };
    float*    base_f = (float*)d_ws;
    int*      base_i = (int*)d_ws;
    unsigned* base_u = (unsigned*)d_ws;
    float*    dinv     = base_f + alloc(N);
    int*      deg      = base_i + alloc(N);      // reused as cursor
    int*      row_ptr  = base_i + alloc(N + 1);
    int*      bsums    = base_i + alloc(1024);
    int*      csr_src  = base_i + alloc(E);
    float*    csr_norm = base_f + alloc(E);
    unsigned* h1bf     = base_u + alloc((size_t)N * 32);  // N x 64 bf16
    unsigned* h2bf     = base_u + alloc((size_t)N * 32);
    unsigned* x1bf     = base_u + alloc((size_t)N * 32);
    unsigned* x2bf     = base_u + alloc((size_t)N * 32);
    // W fragment buffers (uint4 = 4 uints): sizes in uints
    uint4*    wf1a = (uint4*)(base_u + alloc((D1 / 32) * 2 * 256 * 4));  // 32768 uints
    uint4*    wf1b = (uint4*)(base_u + alloc((D2 / 32) * 2 * 256 * 4));  // 16384
    uint4*    wf2a = (uint4*)(base_u + alloc((H  / 32) * 2 * 256 * 4));  // 4096
    uint4*    wf2b = (uint4*)(base_u + alloc((H  / 32) * 2 * 256 * 4));  // 4096
    int*      cursor = deg;

    dim3 blk(256);
    dim3 grid_e(ceil_div(E, 256));
    dim3 grid_n(ceil_div(N, 256));
    dim3 grid_agg(ceil_div(N, 8));
    dim3 grid_gemm(ceil_div(N, 64));

    // ---- CSR build + dinv + edge norms ----
    hipMemsetAsync(deg, 0, (size_t)N * sizeof(int), stream);
    deg_kernel<<<grid_e, blk, 0, stream>>>(dst, deg, E);
    dinv_kernel<<<grid_n, blk, 0, stream>>>(deg, dinv, N);
    scan_block_kernel<<<nblocks_scan, blk, 0, stream>>>(deg, row_ptr, bsums, N);
    scan_top_kernel<<<1, 512, 0, stream>>>(bsums, nblocks_scan);
    scan_add_kernel<<<grid_n, blk, 0, stream>>>(row_ptr, bsums, cursor, N, E);
    scatter_kernel<<<grid_e, blk, 0, stream>>>(src, dst, dinv, cursor, csr_src, csr_norm, E);

    // ---- W fragment pre-pack ----
    wfrag_kernel<<<ceil_div((D1 / 32) * 256, 256), blk, 0, stream>>>(W1a, wf1a, D1);
    wfrag_kernel<<<ceil_div((D2 / 32) * 256, 256), blk, 0, stream>>>(W1b, wf1b, D2);
    wfrag_kernel<<<ceil_div((H  / 32) * 256, 256), blk, 0, stream>>>(W2a, wf2a, H);
    wfrag_kernel<<<ceil_div((H  / 32) * 256, 256), blk, 0, stream>>>(W2b, wf2b, H);

    // ---- layer 1, both branches ----
    gemm_l1_kernel<<<grid_gemm, blk, 0, stream>>>(x_omic1, wf1a, h1bf, N, D1);
    gemm_l1_kernel<<<grid_gemm, blk, 0, stream>>>(x_omic2, wf1b, h2bf, N, D2);
    agg2_kernel<<<grid_agg, blk, 0, stream>>>(h1bf, h2bf, dinv, row_ptr, csr_src, csr_norm,
                                              b1a, b1b, x1bf, x2bf,
                                              nullptr, nullptr, nullptr, N);
    // ---- layer 2, both branches + fused FC ----
    gemm_l2_kernel<<<grid_gemm, blk, 0, stream>>>((const uint4*)x1bf, wf2a, h1bf, N);
    gemm_l2_kernel<<<grid_gemm, blk, 0, stream>>>((const uint4*)x2bf, wf2b, h2bf, N);
    agg2_kernel<<<grid_agg, blk, 0, stream>>>(h1bf, h2bf, dinv, row_ptr, csr_src, csr_norm,
                                              b2a, b2b, nullptr, nullptr,
                                              Wfc, bfc, out, N);
}

// Round 6
// 733.348 us; speedup vs baseline: 3.0432x; 1.1502x over previous
//
#include <hip/hip_runtime.h>
#include <hip/hip_bf16.h>
#include <math.h>

// ---------------------------------------------------------------------------
// MoGCN: two 2-layer GCN branches (H=64) + concat + FC(128->4), fp32 in/out.
// Round 5:
//   - CSR build rewritten: LDS-bucketed two-pass counting sort (no per-edge
//     global atomics, no random 4B scatter). Replaces deg/dinv/scan/scatter.
//   - csr_norm dropped: agg gathers dinv[src] from the hot 400 KB table.
//   - GEMMs: MFMA bf16 split-precision (unchanged from R4).
// ---------------------------------------------------------------------------

#define H 64
#define BCAP 16384            // per-bucket capacity (avg fill ~4096, +190 sigma)

static inline int ceil_div(int a, int b) { return (a + b - 1) / b; }

typedef __attribute__((ext_vector_type(8))) short short8_t;  // 8 bf16
typedef __attribute__((ext_vector_type(4))) float f32x4;

__device__ inline unsigned short f2bf_rne(float f) {
    unsigned u = __float_as_uint(f);
    u += 0x7fffu + ((u >> 16) & 1u);
    return (unsigned short)(u >> 16);
}
__device__ inline unsigned pk_bf(float a, float b) {
    return (unsigned)f2bf_rne(a) | ((unsigned)f2bf_rne(b) << 16);
}
__device__ inline float2 bf2x(unsigned w) {
    float2 r;
    r.x = __uint_as_float(w << 16);
    r.y = __uint_as_float(w & 0xffff0000u);
    return r;
}
union V8 { uint4 u4; unsigned u[4]; short8_t s; };

// ---- pass 1: bucket edges by dst>>8 (packed src | dlocal<<17) -------------
// 2048 edges/block; LDS histogram; one cursor atomic per (block,bucket).
__global__ __launch_bounds__(256) void bucket_scatter_kernel(
        const int* __restrict__ src, const int* __restrict__ dst,
        int* __restrict__ cursor, unsigned* __restrict__ bucketed,
        int E, int nbkt) {
    __shared__ int lcnt[512];
    __shared__ int lbase[512];
    const int t = threadIdx.x;
    for (int b = t; b < nbkt; b += 256) lcnt[b] = 0;
    __syncthreads();

    unsigned val[8];
    int bkt[8], lpos[8];
    const int e0 = blockIdx.x * 2048;
#pragma unroll
    for (int k = 0; k < 8; ++k) {
        int e = e0 + k * 256 + t;
        bkt[k] = -1;
        if (e < E) {
            int s = src[e];
            int d = dst[e];
            int b = d >> 8;
            val[k] = (unsigned)s | ((unsigned)(d & 255) << 17);
            bkt[k] = b;
            lpos[k] = atomicAdd(&lcnt[b], 1);
        }
    }
    __syncthreads();
    for (int b = t; b < nbkt; b += 256) {
        int c = lcnt[b];
        lbase[b] = c > 0 ? atomicAdd(&cursor[b], c) : 0;
    }
    __syncthreads();
#pragma unroll
    for (int k = 0; k < 8; ++k) {
        if (bkt[k] >= 0) {
            int p = lbase[bkt[k]] + lpos[k];
            if (p < BCAP)  // impossible overflow guard (keeps writes in range)
                bucketed[(size_t)bkt[k] * BCAP + p] = val[k];
        }
    }
}

// ---- pass 2: exclusive scan of bucket totals -> bucket_base ---------------
__global__ __launch_bounds__(512) void bucket_scan_kernel(
        const int* __restrict__ cursor, int* __restrict__ bucket_base,
        int* __restrict__ row_ptr, int nbkt, int N, int E) {
    __shared__ int s[512];
    const int t = threadIdx.x;
    int v = (t < nbkt) ? cursor[t] : 0;
    s[t] = v;
    __syncthreads();
#pragma unroll
    for (int off = 1; off < 512; off <<= 1) {
        int u = (t >= off) ? s[t - off] : 0;
        __syncthreads();
        s[t] += u;
        __syncthreads();
    }
    if (t < nbkt) bucket_base[t] = s[t] - v;
    if (t == 0) row_ptr[N] = E;
}

// ---- pass 3: per-bucket exact CSR + row_ptr + dinv ------------------------
// one block per bucket (256 dst nodes, ~4K edges). Dense coalesced IO.
__global__ __launch_bounds__(256) void bucket_csr_kernel(
        const unsigned* __restrict__ bucketed, const int* __restrict__ cursor,
        const int* __restrict__ bucket_base, int* __restrict__ csr_src,
        int* __restrict__ row_ptr, float* __restrict__ dinv, int N) {
    __shared__ int dcnt[256];
    __shared__ int dbase[256];
    __shared__ int dcur[256];
    const int t = threadIdx.x;
    const int b = blockIdx.x;
    const int cnt = min(cursor[b], BCAP);
    const int base = bucket_base[b];
    const unsigned* bed = bucketed + (size_t)b * BCAP;

    dcnt[t] = 0;
    __syncthreads();
    for (int i = t; i < cnt; i += 256) {
        unsigned v = bed[i];
        atomicAdd(&dcnt[v >> 17], 1);
    }
    __syncthreads();
    int myc = dcnt[t];
    // exclusive scan over 256 (Hillis-Steele, in place)
    int acc = myc;
    dbase[t] = acc;
    __syncthreads();
#pragma unroll
    for (int off = 1; off < 256; off <<= 1) {
        int u = (t >= off) ? dbase[t - off] : 0;
        __syncthreads();
        dbase[t] += u;
        __syncthreads();
    }
    int excl = dbase[t] - myc;
    dcur[t] = excl;
    int node = b * 256 + t;
    if (node < N) {
        row_ptr[node] = base + excl;
        dinv[node] = rsqrtf((float)myc + 1.0f);  // +1 self loop
    }
    __syncthreads();
    for (int i = t; i < cnt; i += 256) {
        unsigned v = bed[i];
        int dl = v >> 17;
        int p = atomicAdd(&dcur[dl], 1);
        csr_src[base + p] = (int)(v & 0x1FFFFu);
    }
}

// ---- W fragment pre-pack: W[K][64] fp32 -> hi/lo bf16 MFMA lane order -----
__global__ __launch_bounds__(256) void wfrag_kernel(const float* __restrict__ W,
                                                    uint4* __restrict__ frag, int K) {
    int t = blockIdx.x * 256 + threadIdx.x;
    int total = (K >> 5) * 256;
    if (t >= total) return;
    int lane = t & 63, nt = (t >> 6) & 3, ks = t >> 8;
    int nl = lane & 15, q = lane >> 4;
    float hi[8], lo[8];
#pragma unroll
    for (int j = 0; j < 8; ++j) {
        float w = W[(size_t)(ks * 32 + q * 8 + j) * 64 + nt * 16 + nl];
        unsigned hb = f2bf_rne(w);
        float hf = __uint_as_float(((unsigned)hb) << 16);
        hi[j] = hf;
        lo[j] = w - hf;
    }
    V8 vh, vl;
#pragma unroll
    for (int j = 0; j < 4; ++j) {
        vh.u[j] = pk_bf(hi[2 * j], hi[2 * j + 1]);
        vl.u[j] = pk_bf(lo[2 * j], lo[2 * j + 1]);
    }
    size_t base = (size_t)((ks * 4 + nt) * 2) * 64 + lane;
    frag[base] = vh.u4;
    frag[base + 64] = vl.u4;
}

// ---- layer-1 GEMM: Hout_bf16[M,64] = X_fp32[M,K] @ W (bf16x3 split) -------
__global__ __launch_bounds__(256) void gemm_l1_kernel(const float* __restrict__ X,
                                                      const uint4* __restrict__ wf,
                                                      unsigned* __restrict__ Hout,
                                                      int M, int K) {
    const int tid = threadIdx.x;
    const int w = tid >> 6, l = tid & 63;
    const int m = l & 15, q = l >> 4;
    const int tile = blockIdx.x * 64 + w * 16;
    int row = tile + m;
    int rowc = row < M ? row : M - 1;
    const float* Xr = X + (size_t)rowc * K;

    f32x4 acc[4];
#pragma unroll
    for (int nt = 0; nt < 4; ++nt) acc[nt] = (f32x4){0.f, 0.f, 0.f, 0.f};

    const int ksteps = K >> 5;
    for (int ks = 0; ks < ksteps; ++ks) {
        const float4 f0 = *(const float4*)&Xr[ks * 32 + q * 8];
        const float4 f1 = *(const float4*)&Xr[ks * 32 + q * 8 + 4];
        float xs[8] = {f0.x, f0.y, f0.z, f0.w, f1.x, f1.y, f1.z, f1.w};
        V8 ah, al;
#pragma unroll
        for (int j = 0; j < 4; ++j) {
            float a = xs[2 * j], b = xs[2 * j + 1];
            unsigned ha = f2bf_rne(a), hb = f2bf_rne(b);
            float fa = __uint_as_float(ha << 16);
            float fb = __uint_as_float(hb << 16);
            ah.u[j] = ha | (hb << 16);
            al.u[j] = pk_bf(a - fa, b - fb);
        }
        const uint4* base = wf + (size_t)(ks * 4) * 2 * 64 + l;
#pragma unroll
        for (int nt = 0; nt < 4; ++nt) {
            V8 bh, bl;
            bh.u4 = base[(size_t)(nt * 2) * 64];
            bl.u4 = base[(size_t)(nt * 2 + 1) * 64];
            acc[nt] = __builtin_amdgcn_mfma_f32_16x16x32_bf16(ah.s, bh.s, acc[nt], 0, 0, 0);
            acc[nt] = __builtin_amdgcn_mfma_f32_16x16x32_bf16(al.s, bh.s, acc[nt], 0, 0, 0);
            acc[nt] = __builtin_amdgcn_mfma_f32_16x16x32_bf16(ah.s, bl.s, acc[nt], 0, 0, 0);
        }
    }

    const int rbase = tile + q * 4;
#pragma unroll
    for (int nt = 0; nt < 4; ++nt) {
#pragma unroll
        for (int i = 0; i < 4; ++i) {
            float f = acc[nt][i];
            float fo = __shfl_xor(f, 1, 64);
            int r = rbase + i;
            if (((l & 1) == 0) && r < M)
                Hout[(size_t)r * 32 + nt * 8 + (m >> 1)] = pk_bf(f, fo);
        }
    }
}

// ---- layer-2 GEMM: Hout_bf16[M,64] = X_bf16[M,64] @ W (W split, 2 MFMA) ---
__global__ __launch_bounds__(256) void gemm_l2_kernel(const uint4* __restrict__ Xb,
                                                      const uint4* __restrict__ wf,
                                                      unsigned* __restrict__ Hout,
                                                      int M) {
    const int tid = threadIdx.x;
    const int w = tid >> 6, l = tid & 63;
    const int m = l & 15, q = l >> 4;
    const int tile = blockIdx.x * 64 + w * 16;
    int row = tile + m;
    int rowc = row < M ? row : M - 1;

    f32x4 acc[4];
#pragma unroll
    for (int nt = 0; nt < 4; ++nt) acc[nt] = (f32x4){0.f, 0.f, 0.f, 0.f};

#pragma unroll
    for (int ks = 0; ks < 2; ++ks) {
        V8 av;
        av.u4 = Xb[(size_t)rowc * 8 + ks * 4 + q];
        const uint4* base = wf + (size_t)(ks * 4) * 2 * 64 + l;
#pragma unroll
        for (int nt = 0; nt < 4; ++nt) {
            V8 bh, bl;
            bh.u4 = base[(size_t)(nt * 2) * 64];
            bl.u4 = base[(size_t)(nt * 2 + 1) * 64];
            acc[nt] = __builtin_amdgcn_mfma_f32_16x16x32_bf16(av.s, bh.s, acc[nt], 0, 0, 0);
            acc[nt] = __builtin_amdgcn_mfma_f32_16x16x32_bf16(av.s, bl.s, acc[nt], 0, 0, 0);
        }
    }

    const int rbase = tile + q * 4;
#pragma unroll
    for (int nt = 0; nt < 4; ++nt) {
#pragma unroll
        for (int i = 0; i < 4; ++i) {
            float f = acc[nt][i];
            float fo = __shfl_xor(f, 1, 64);
            int r = rbase + i;
            if (((l & 1) == 0) && r < M)
                Hout[(size_t)r * 32 + nt * 8 + (m >> 1)] = pk_bf(f, fo);
        }
    }
}

// ---- fused dual-branch aggregation: selfloop+gather+bias+ELU [+FC] --------
// 2 dst nodes per wave; lane l holds features (2l,2l+1) as packed bf16.
// edge norm computed from the hot dinv table (no csr_norm stream).
__global__ __launch_bounds__(256) void agg2_kernel(const unsigned* __restrict__ h1,
                                                   const unsigned* __restrict__ h2,
                                                   const float* __restrict__ dinv,
                                                   const int* __restrict__ row_ptr,
                                                   const int* __restrict__ csr_src,
                                                   const float* __restrict__ b1,
                                                   const float* __restrict__ b2,
                                                   unsigned* __restrict__ o1,
                                                   unsigned* __restrict__ o2,
                                                   const float* __restrict__ Wfc,
                                                   const float* __restrict__ bfc,
                                                   float* __restrict__ out, int n) {
    const int tid  = threadIdx.x;
    const int lane = tid & 63;
    const int wave = tid >> 6;
    const int half = lane >> 5;
    const int l    = lane & 31;
    const int hb   = half << 5;
    const int node = blockIdx.x * 8 + wave * 2 + half;
    const bool active = (node < n);

    int r0 = 0, r1 = 0;
    float di = 0.f;
    if (active) { r0 = row_ptr[node]; r1 = row_ptr[node + 1]; di = dinv[node]; }
    const float di2 = di * di;
    const int rowoff = node * 32 + l;

    float2 acc1 = make_float2(0.f, 0.f), acc2 = make_float2(0.f, 0.f);
    if (active) {
        float2 s1 = bf2x(h1[rowoff]);
        float2 s2 = bf2x(h2[rowoff]);
        acc1.x = s1.x * di2; acc1.y = s1.y * di2;
        acc2.x = s2.x * di2; acc2.y = s2.y * di2;
    }

    for (int base = r0; base < r1; base += 32) {
        int cnt = r1 - base;
        if (cnt > 32) cnt = 32;
        int j = base + (l < cnt ? l : cnt - 1);   // coalesced chunk prefetch
        int sj = csr_src[j];
        float dsj = dinv[sj];                     // hot 400 KB table
#pragma unroll 4
        for (int t = 0; t < cnt; ++t) {
            int s    = __shfl(sj, hb | t, 64);
            float nr = __shfl(dsj, hb | t, 64) * di;
            float2 g1 = bf2x(h1[s * 32 + l]);
            float2 g2 = bf2x(h2[s * 32 + l]);
            acc1.x = fmaf(g1.x, nr, acc1.x);
            acc1.y = fmaf(g1.y, nr, acc1.y);
            acc2.x = fmaf(g2.x, nr, acc2.x);
            acc2.y = fmaf(g2.y, nr, acc2.y);
        }
    }

    float2 bv1 = ((const float2*)b1)[l];
    float2 bv2 = ((const float2*)b2)[l];
    float2 v1, v2;
    v1.x = acc1.x + bv1.x; v1.y = acc1.y + bv1.y;
    v2.x = acc2.x + bv2.x; v2.y = acc2.y + bv2.y;
    v1.x = v1.x > 0.f ? v1.x : (expf(v1.x) - 1.f);
    v1.y = v1.y > 0.f ? v1.y : (expf(v1.y) - 1.f);
    v2.x = v2.x > 0.f ? v2.x : (expf(v2.x) - 1.f);
    v2.y = v2.y > 0.f ? v2.y : (expf(v2.y) - 1.f);

    if (Wfc == nullptr) {
        if (active) {
            o1[rowoff] = pk_bf(v1.x, v1.y);
            o2[rowoff] = pk_bf(v2.x, v2.y);
        }
        return;
    }

    // fused FC head
    const float* Wp1 = &Wfc[(2 * l) * 4];
    const float* Wp2 = &Wfc[(H + 2 * l) * 4];
    float a[4];
#pragma unroll
    for (int c = 0; c < 4; ++c)
        a[c] = v1.x * Wp1[c] + v1.y * Wp1[4 + c] + v2.x * Wp2[c] + v2.y * Wp2[4 + c];
#pragma unroll
    for (int off = 16; off > 0; off >>= 1) {
#pragma unroll
        for (int c = 0; c < 4; ++c)
            a[c] += __shfl_down(a[c], off, 64);
    }
    if (l == 0 && active) {
#pragma unroll
        for (int c = 0; c < 4; ++c)
            out[(size_t)node * 4 + c] = a[c] + bfc[c];
    }
}

// ---------------------------------------------------------------------------
extern "C" void kernel_launch(void* const* d_in, const int* in_sizes, int n_in,
                              void* d_out, int out_size, void* d_ws, size_t ws_size,
                              hipStream_t stream) {
    const float* x_omic1 = (const float*)d_in[0];
    const float* x_omic2 = (const float*)d_in[1];
    const int*   eidx    = (const int*)d_in[2];
    const float* W1a = (const float*)d_in[3];
    const float* b1a = (const float*)d_in[4];
    const float* W2a = (const float*)d_in[5];
    const float* b2a = (const float*)d_in[6];
    const float* W1b = (const float*)d_in[7];
    const float* b1b = (const float*)d_in[8];
    const float* W2b = (const float*)d_in[9];
    const float* b2b = (const float*)d_in[10];
    const float* Wfc = (const float*)d_in[11];
    const float* bfc = (const float*)d_in[12];
    float* out = (float*)d_out;

    const int D1 = 512, D2 = 256;
    const int N = in_sizes[0] / D1;
    const int E = in_sizes[2] / 2;
    const int* src = eidx;
    const int* dst = eidx + E;
    const int nbkt = ceil_div(N, 256);   // 391 for N=100000 (must be <= 512)

    // workspace layout (4B units, 16B-aligned chunks)
    size_t off = 0;
    auto alloc = [&](size_t elems) { size_t o = off; off += (elems + 3) & ~(size_t)3; return o; };
    float*    base_f = (float*)d_ws;
    int*      base_i = (int*)d_ws;
    unsigned* base_u = (unsigned*)d_ws;
    float*    dinv     = base_f + alloc(N);
    int*      row_ptr  = base_i + alloc(N + 1);
    int*      cursor   = base_i + alloc(512);
    int*      bkbase   = base_i + alloc(512);
    unsigned* bucketed = base_u + alloc((size_t)nbkt * BCAP);
    int*      csr_src  = base_i + alloc(E);
    unsigned* h1bf     = base_u + alloc((size_t)N * 32);  // N x 64 bf16
    unsigned* h2bf     = base_u + alloc((size_t)N * 32);
    unsigned* x1bf     = base_u + alloc((size_t)N * 32);
    unsigned* x2bf     = base_u + alloc((size_t)N * 32);
    uint4*    wf1a = (uint4*)(base_u + alloc((D1 / 32) * 2 * 256 * 4));
    uint4*    wf1b = (uint4*)(base_u + alloc((D2 / 32) * 2 * 256 * 4));
    uint4*    wf2a = (uint4*)(base_u + alloc((H  / 32) * 2 * 256 * 4));
    uint4*    wf2b = (uint4*)(base_u + alloc((H  / 32) * 2 * 256 * 4));

    dim3 blk(256);
    dim3 grid_agg(ceil_div(N, 8));
    dim3 grid_gemm(ceil_div(N, 64));

    // ---- CSR build (bucketed counting sort) ----
    hipMemsetAsync(cursor, 0, 512 * sizeof(int), stream);
    bucket_scatter_kernel<<<ceil_div(E, 2048), blk, 0, stream>>>(src, dst, cursor,
                                                                 bucketed, E, nbkt);
    bucket_scan_kernel<<<1, 512, 0, stream>>>(cursor, bkbase, row_ptr, nbkt, N, E);
    bucket_csr_kernel<<<nbkt, blk, 0, stream>>>(bucketed, cursor, bkbase,
                                                csr_src, row_ptr, dinv, N);

    // ---- W fragment pre-pack ----
    wfrag_kernel<<<ceil_div((D1 / 32) * 256, 256), blk, 0, stream>>>(W1a, wf1a, D1);
    wfrag_kernel<<<ceil_div((D2 / 32) * 256, 256), blk, 0, stream>>>(W1b, wf1b, D2);
    wfrag_kernel<<<ceil_div((H  / 32) * 256, 256), blk, 0, stream>>>(W2a, wf2a, H);
    wfrag_kernel<<<ceil_div((H  / 32) * 256, 256), blk, 0, stream>>>(W2b, wf2b, H);

    // ---- layer 1, both branches ----
    gemm_l1_kernel<<<grid_gemm, blk, 0, stream>>>(x_omic1, wf1a, h1bf, N, D1);
    gemm_l1_kernel<<<grid_gemm, blk, 0, stream>>>(x_omic2, wf1b, h2bf, N, D2);
    agg2_kernel<<<grid_agg, blk, 0, stream>>>(h1bf, h2bf, dinv, row_ptr, csr_src,
                                              b1a, b1b, x1bf, x2bf,
                                              nullptr, nullptr, nullptr, N);
    // ---- layer 2, both branches + fused FC ----
    gemm_l2_kernel<<<grid_gemm, blk, 0, stream>>>((const uint4*)x1bf, wf2a, h1bf, N);
    gemm_l2_kernel<<<grid_gemm, blk, 0, stream>>>((const uint4*)x2bf, wf2b, h2bf, N);
    agg2_kernel<<<grid_agg, blk, 0, stream>>>(h1bf, h2bf, dinv, row_ptr, csr_src,
                                              b2a, b2b, nullptr, nullptr,
                                              Wfc, bfc, out, N);
}